// Round 4
// baseline (107.388 us; speedup 1.0000x reference)
//
#include <hip/hip_runtime.h>
#include <hip/hip_bf16.h>

// Problem constants (fixed by the reference):
//   B=16, T=1024 -> BT=16384 rows; C=512 phones; A=4096 arcs; P=256 phonemes.
#define BT   16384
#define CDIM 512
#define ADIM 4096
#define PDIM 256

typedef __attribute__((ext_vector_type(8))) short  short8;   // 8 x bf16 (4 VGPRs)
typedef __attribute__((ext_vector_type(8))) unsigned short ushort8;
typedef __attribute__((ext_vector_type(4))) float  f32x4;    // 4 x fp32 acc

// fp32 -> bf16 round-to-nearest-even (values are positive finite)
__device__ __forceinline__ unsigned short bf16_rne(float f) {
    unsigned int u = __float_as_uint(f);
    u += 0x7FFFu + ((u >> 16) & 1u);
    return (unsigned short)(u >> 16);
}

// ---------------------------------------------------------------------------
// Kernel 1: W build. 16 blocks x 32 phones. Each block scans the 4096 arcs
// once (labels read 16x total, not 512x), accumulates W[c][p] in LDS, then
// emits one full kb-slab of the bf16 B-fragment-major layout:
//   Wf[kb][n][kin], kb = c>>5, kin = c&31;  block bx owns kb = bx.
// ---------------------------------------------------------------------------
__global__ __launch_bounds__(256) void build_Wf(const float* __restrict__ alloW,
                                                const int* __restrict__ phone_lab,
                                                const int* __restrict__ phoneme_lab,
                                                unsigned short* __restrict__ Wf) {
    __shared__ float wrow[32 * PDIM];   // 32 KB: [phone-within-block][phoneme]
    const int bx = blockIdx.x;          // 0..15 == kb
    const int t  = threadIdx.x;

#pragma unroll
    for (int i = 0; i < 32; ++i) wrow[i * 256 + t] = 0.0f;
    __syncthreads();

#pragma unroll
    for (int i = 0; i < ADIM / 256; ++i) {
        int a = i * 256 + t;
        int c = phone_lab[a];
        if ((c >> 5) == bx)
            atomicAdd(&wrow[(c & 31) * 256 + phoneme_lab[a]], __expf(alloW[a]));
    }
    __syncthreads();

    // thread t emits phoneme n=t: Wf[bx][t][0..31] (64 B contiguous)
    ushort8 pk[4];
#pragma unroll
    for (int g = 0; g < 4; ++g) {
#pragma unroll
        for (int j = 0; j < 8; ++j)
            pk[g][j] = bf16_rne(wrow[(g * 8 + j) * 256 + t]);
    }
    unsigned short* dst = Wf + (size_t)bx * (PDIM * 32) + t * 32;
#pragma unroll
    for (int g = 0; g < 4; ++g)
        *(ushort8*)(dst + g * 8) = pk[g];
}

// ---------------------------------------------------------------------------
// Kernel 2: fused exp + GEMM + redistribute + log.
// Block: 256 thr (4 waves), tile 16 rows x 256 cols. Grid 1024 -> 4 blk/CU,
// 16 waves/CU (2x round-3 occupancy for latency hiding).
//
// Prologue: thread (c=lane>>2, j=lane&3) of wave w handles rows c, k-slabs
// kb=w*4+i; each iteration: 32B global read, 8 exp, one 16B ds_write_b128
// into A-frag layout Af[kb][c][kin] — each wave instruction tiles a
// contiguous 1 KB slab (conflict-free). Row Z via 4-lane shfl + LDS atomic.
// No max-subtract (|hs| < ~5.5 -> exp safely in fp32 range); 1/Z folded
// into the epilogue by linearity.
//
// K-loop: A from LDS (1 ds_read_b128), B from global Wf (frag-major, L2-hot),
// 4 MFMA 16x16x32 per wave per kb. No barriers inside.
//
// Epilogue: rowsum across cols (shfl + tiny LDS), then
// out = log(u*invZ - (S*invZ - 1)/P).
// ---------------------------------------------------------------------------
__global__ __launch_bounds__(256, 4) void allo_fused(const float* __restrict__ hs,
                                                     const unsigned short* __restrict__ Wf,
                                                     float* __restrict__ out) {
    __shared__ __align__(16) unsigned short Af[16 * 512];  // 16 KB [kb][c][kin]
    __shared__ float sZ[16];
    __shared__ float psum[4][16];

    const int tid  = threadIdx.x;
    const int wave = tid >> 6;
    const int lane = tid & 63;
    const int row0 = blockIdx.x * 16;

    if (tid < 16) sZ[tid] = 0.0f;
    __syncthreads();

    // ---- prologue ----
    {
        const int pc = lane >> 2;   // row within tile, 0..15
        const int pj = lane & 3;    // 8-element k-slice within kb
        const float* hsr = hs + (size_t)(row0 + pc) * CDIM + pj * 8;
        unsigned short* af = Af + pc * 32 + pj * 8;

        float s = 0.0f;
#pragma unroll
        for (int i = 0; i < 4; ++i) {
            const int kb = wave * 4 + i;
            float4 v0 = *(const float4*)(hsr + kb * 32);
            float4 v1 = *(const float4*)(hsr + kb * 32 + 4);
            float e0 = __expf(v0.x), e1 = __expf(v0.y);
            float e2 = __expf(v0.z), e3 = __expf(v0.w);
            float e4 = __expf(v1.x), e5 = __expf(v1.y);
            float e6 = __expf(v1.z), e7 = __expf(v1.w);
            s += ((e0 + e1) + (e2 + e3)) + ((e4 + e5) + (e6 + e7));
            ushort8 pk;
            pk[0] = bf16_rne(e0); pk[1] = bf16_rne(e1);
            pk[2] = bf16_rne(e2); pk[3] = bf16_rne(e3);
            pk[4] = bf16_rne(e4); pk[5] = bf16_rne(e5);
            pk[6] = bf16_rne(e6); pk[7] = bf16_rne(e7);
            *(ushort8*)(af + kb * 512) = pk;
        }
        s += __shfl_xor(s, 1);
        s += __shfl_xor(s, 2);
        if (pj == 0) atomicAdd(&sZ[pc], s);
    }
    __syncthreads();

    // ---- MFMA K-loop ----
    const int c = lane & 15;
    const int q = lane >> 4;

    f32x4 acc[4];
#pragma unroll
    for (int cb = 0; cb < 4; ++cb) acc[cb] = (f32x4){0.f, 0.f, 0.f, 0.f};

    const unsigned short* wb  = Wf + (size_t)(wave * 64 + c) * 32 + q * 8;
    const unsigned short* af0 = Af + c * 32 + q * 8;

#pragma unroll 4
    for (int kb = 0; kb < 16; ++kb) {
        short8 a0 = *(const short8*)(af0 + kb * 512);
        const unsigned short* wkb = wb + kb * 8192;
        short8 b0 = *(const short8*)(wkb);
        short8 b1 = *(const short8*)(wkb + 512);
        short8 b2 = *(const short8*)(wkb + 1024);
        short8 b3 = *(const short8*)(wkb + 1536);

        acc[0] = __builtin_amdgcn_mfma_f32_16x16x32_bf16(a0, b0, acc[0], 0, 0, 0);
        acc[1] = __builtin_amdgcn_mfma_f32_16x16x32_bf16(a0, b1, acc[1], 0, 0, 0);
        acc[2] = __builtin_amdgcn_mfma_f32_16x16x32_bf16(a0, b2, acc[2], 0, 0, 0);
        acc[3] = __builtin_amdgcn_mfma_f32_16x16x32_bf16(a0, b3, acc[3], 0, 0, 0);
    }

    // ---- epilogue ----
    // C/D mapping (m89/m91): col = lane&15 (=c), row = q*4 + reg.
    {
        float v[4];
#pragma unroll
        for (int r = 0; r < 4; ++r) {
            float x = (acc[0][r] + acc[1][r]) + (acc[2][r] + acc[3][r]);
            x += __shfl_xor(x, 1);
            x += __shfl_xor(x, 2);
            x += __shfl_xor(x, 4);
            x += __shfl_xor(x, 8);
            v[r] = x;   // this wave's 64-col partial for row q*4+r
        }
        if (c == 0) {
#pragma unroll
            for (int r = 0; r < 4; ++r) psum[wave][q * 4 + r] = v[r];
        }
    }
    __syncthreads();

#pragma unroll
    for (int r = 0; r < 4; ++r) {
        const int rr = q * 4 + r;
        const float iz = 1.0f / sZ[rr];
        const float S  = ((psum[0][rr] + psum[1][rr]) + (psum[2][rr] + psum[3][rr])) * iz;
        const float corr = (S - 1.0f) * (1.0f / (float)PDIM);
        float* orow = out + (size_t)(row0 + rr) * PDIM + wave * 64 + c;
#pragma unroll
        for (int cb = 0; cb < 4; ++cb)
            orow[cb * 16] = __logf(acc[cb][r] * iz - corr);
    }
}

// ---------------------------------------------------------------------------
extern "C" void kernel_launch(void* const* d_in, const int* in_sizes, int n_in,
                              void* d_out, int out_size, void* d_ws, size_t ws_size,
                              hipStream_t stream) {
    const float* hs          = (const float*)d_in[0];  // [BT, C]
    const float* alloW       = (const float*)d_in[1];  // [A]
    const int*   phone_lab   = (const int*)d_in[2];    // [A]
    const int*   phoneme_lab = (const int*)d_in[3];    // [A]
    float*       out         = (float*)d_out;          // [BT, P]

    unsigned short* Wf = (unsigned short*)d_ws;        // 256 KB, fully rewritten

    build_Wf<<<CDIM / 32, 256, 0, stream>>>(alloW, phone_lab, phoneme_lab, Wf);
    allo_fused<<<BT / 16, 256, 0, stream>>>(hs, Wf, out);
}

// Round 5
// 100.162 us; speedup vs baseline: 1.0721x; 1.0721x over previous
//
#include <hip/hip_runtime.h>
#include <hip/hip_bf16.h>

// Problem constants (fixed by the reference):
//   B=16, T=1024 -> BT=16384 rows; C=512 phones; A=4096 arcs; P=256 phonemes.
#define BT   16384
#define CDIM 512
#define ADIM 4096
#define PDIM 256

typedef __attribute__((ext_vector_type(8))) short  short8;   // 8 x bf16 (4 VGPRs)
typedef __attribute__((ext_vector_type(8))) unsigned short ushort8;
typedef __attribute__((ext_vector_type(4))) float  f32x4;    // 4 x fp32 acc

// fp32 -> bf16 round-to-nearest-even (values are positive finite)
__device__ __forceinline__ unsigned short bf16_rne(float f) {
    unsigned int u = __float_as_uint(f);
    u += 0x7FFFu + ((u >> 16) & 1u);
    return (unsigned short)(u >> 16);
}

// ---------------------------------------------------------------------------
// Kernel 1: W build. 16 blocks x 32 phones. Each block scans the 4096 arcs
// once (labels read 16x total), accumulates W[c][p] in LDS, then emits one
// full kb-slab of the bf16 B-fragment-major layout:
//   Wf[kb][n][kin], kb = c>>5, kin = c&31;  block bx owns kb = bx.
// ---------------------------------------------------------------------------
__global__ __launch_bounds__(256) void build_Wf(const float* __restrict__ alloW,
                                                const int* __restrict__ phone_lab,
                                                const int* __restrict__ phoneme_lab,
                                                unsigned short* __restrict__ Wf) {
    __shared__ float wrow[32 * PDIM];   // 32 KB: [phone-within-block][phoneme]
    const int bx = blockIdx.x;          // 0..15 == kb
    const int t  = threadIdx.x;

#pragma unroll
    for (int i = 0; i < 32; ++i) wrow[i * 256 + t] = 0.0f;
    __syncthreads();

#pragma unroll
    for (int i = 0; i < ADIM / 256; ++i) {
        int a = i * 256 + t;
        int c = phone_lab[a];
        if ((c >> 5) == bx)
            atomicAdd(&wrow[(c & 31) * 256 + phoneme_lab[a]], __expf(alloW[a]));
    }
    __syncthreads();

    // thread t emits phoneme n=t: Wf[bx][t][0..31] (64 B contiguous)
    ushort8 pk[4];
#pragma unroll
    for (int g = 0; g < 4; ++g) {
#pragma unroll
        for (int j = 0; j < 8; ++j)
            pk[g][j] = bf16_rne(wrow[(g * 8 + j) * 256 + t]);
    }
    unsigned short* dst = Wf + (size_t)bx * (PDIM * 32) + t * 32;
#pragma unroll
    for (int g = 0; g < 4; ++g)
        *(ushort8*)(dst + g * 8) = pk[g];
}

// ---------------------------------------------------------------------------
// Kernel 2: fused exp + GEMM + redistribute + log.
// Block: 256 thr (4 waves), tile 32 rows x 256 cols. Grid 512 (2 blocks/CU,
// 8 waves/CU — max possible with full-P tiles at 32 rows).
//
// Prologue: 8 thr/row; hs loads issued in batches of 8 independent float4
// (latency overlapped), e=exp(x) (no max-subtract: |hs|<~5.5), bf16-pack
// into A-frag LDS layout Af[rb][kb][cc][kin]; row Z via 3-step shfl.
// 1/Z applied in epilogue by linearity.
//
// K-loop: manual 2-stage pipeline over 2-kb groups: load group g+1's
// B (global, L2-hot) and A (LDS) while issuing group g's 16 MFMAs —
// keeps 8 B-loads in flight continuously. No barriers inside.
//
// Epilogue: rowsum across cols (shfl + LDS), out = log(u*iz - (S*iz-1)/P).
// ---------------------------------------------------------------------------
__global__ __launch_bounds__(256, 2) void allo_fused(const float* __restrict__ hs,
                                                     const unsigned short* __restrict__ Wf,
                                                     float* __restrict__ out) {
    __shared__ __align__(16) unsigned short Af[2 * 16 * 16 * 32];  // 32 KB
    __shared__ float invZ[32];
    __shared__ float psum[4][32];

    const int tid  = threadIdx.x;
    const int wave = tid >> 6;
    const int lane = tid & 63;
    const int row0 = blockIdx.x * 32;

    // ---- prologue ----
    {
        const int r   = tid >> 3;        // 0..31 (row within tile)
        const int ksl = tid & 7;         // k-slice within each kb
        const int rb  = r >> 4;
        const int cc  = r & 15;
        const float* hsr = hs + (size_t)(row0 + r) * CDIM + ksl * 4;
        unsigned short* af = Af + rb * 8192 + cc * 32 + ksl * 4;

        float s = 0.0f;
#pragma unroll
        for (int h = 0; h < 2; ++h) {          // two batches of 8 kb-slabs
            float4 v[8];
#pragma unroll
            for (int i = 0; i < 8; ++i)
                v[i] = *(const float4*)(hsr + (h * 8 + i) * 32);
#pragma unroll
            for (int i = 0; i < 8; ++i) {
                float e0 = __expf(v[i].x), e1 = __expf(v[i].y);
                float e2 = __expf(v[i].z), e3 = __expf(v[i].w);
                s += (e0 + e1) + (e2 + e3);
                ushort4 pk;
                pk.x = bf16_rne(e0); pk.y = bf16_rne(e1);
                pk.z = bf16_rne(e2); pk.w = bf16_rne(e3);
                *(ushort4*)(af + (h * 8 + i) * 512) = pk;
            }
        }
        s += __shfl_xor(s, 1);
        s += __shfl_xor(s, 2);
        s += __shfl_xor(s, 4);
        if (ksl == 0) invZ[r] = 1.0f / s;
    }
    __syncthreads();

    // ---- MFMA K-loop, 2-stage pipelined over groups of 2 kb ----
    const int c = lane & 15;
    const int q = lane >> 4;

    f32x4 acc[2][4];
#pragma unroll
    for (int rb = 0; rb < 2; ++rb)
#pragma unroll
        for (int cb = 0; cb < 4; ++cb)
            acc[rb][cb] = (f32x4){0.f, 0.f, 0.f, 0.f};

    const unsigned short* wb  = Wf + (size_t)(wave * 64 + c) * 32 + q * 8;
    const unsigned short* af0 = Af + c * 32 + q * 8;

    short8 Bb[2][2][4];   // [stage][iter-in-group][cb]
    short8 Ab[2][2][2];   // [stage][iter-in-group][rb]

#pragma unroll
    for (int it = 0; it < 2; ++it) {
        const unsigned short* wkb = wb + it * 8192;
#pragma unroll
        for (int cb = 0; cb < 4; ++cb)
            Bb[0][it][cb] = *(const short8*)(wkb + cb * 512);
#pragma unroll
        for (int rb = 0; rb < 2; ++rb)
            Ab[0][it][rb] = *(const short8*)(af0 + rb * 8192 + it * 512);
    }

#pragma unroll
    for (int g = 0; g < 8; ++g) {
        const int cur = g & 1, nxt = cur ^ 1;
        if (g < 7) {
            const int kb0 = (g + 1) * 2;
#pragma unroll
            for (int it = 0; it < 2; ++it) {
                const unsigned short* wkb = wb + (size_t)(kb0 + it) * 8192;
#pragma unroll
                for (int cb = 0; cb < 4; ++cb)
                    Bb[nxt][it][cb] = *(const short8*)(wkb + cb * 512);
#pragma unroll
                for (int rb = 0; rb < 2; ++rb)
                    Ab[nxt][it][rb] = *(const short8*)(af0 + rb * 8192 + (kb0 + it) * 512);
            }
        }
#pragma unroll
        for (int it = 0; it < 2; ++it)
#pragma unroll
            for (int rb = 0; rb < 2; ++rb)
#pragma unroll
                for (int cb = 0; cb < 4; ++cb)
                    acc[rb][cb] = __builtin_amdgcn_mfma_f32_16x16x32_bf16(
                        Ab[cur][it][rb], Bb[cur][it][cb], acc[rb][cb], 0, 0, 0);
    }

    // ---- epilogue ----
    // C/D mapping (m89/m91): col = lane&15 (=c), row = q*4 + reg.
    float sv[2][4];
#pragma unroll
    for (int rb = 0; rb < 2; ++rb)
#pragma unroll
        for (int r = 0; r < 4; ++r) {
            float x = (acc[rb][0][r] + acc[rb][1][r]) + (acc[rb][2][r] + acc[rb][3][r]);
            x += __shfl_xor(x, 1);
            x += __shfl_xor(x, 2);
            x += __shfl_xor(x, 4);
            x += __shfl_xor(x, 8);
            sv[rb][r] = x;   // this wave's 64-col partial for row rb*16+q*4+r
        }
    if (c == 0) {
#pragma unroll
        for (int rb = 0; rb < 2; ++rb)
#pragma unroll
            for (int r = 0; r < 4; ++r)
                psum[wave][rb * 16 + q * 4 + r] = sv[rb][r];
    }
    __syncthreads();

#pragma unroll
    for (int rb = 0; rb < 2; ++rb)
#pragma unroll
        for (int r = 0; r < 4; ++r) {
            const int rr = rb * 16 + q * 4 + r;
            const float iz = invZ[rr];
            const float S  = ((psum[0][rr] + psum[1][rr]) + (psum[2][rr] + psum[3][rr])) * iz;
            const float corr = (S - 1.0f) * (1.0f / (float)PDIM);
            float* orow = out + (size_t)(row0 + rr) * PDIM + wave * 64 + c;
#pragma unroll
            for (int cb = 0; cb < 4; ++cb)
                orow[cb * 16] = __logf(acc[rb][cb][r] * iz - corr);
        }
}

// ---------------------------------------------------------------------------
extern "C" void kernel_launch(void* const* d_in, const int* in_sizes, int n_in,
                              void* d_out, int out_size, void* d_ws, size_t ws_size,
                              hipStream_t stream) {
    const float* hs          = (const float*)d_in[0];  // [BT, C]
    const float* alloW       = (const float*)d_in[1];  // [A]
    const int*   phone_lab   = (const int*)d_in[2];    // [A]
    const int*   phoneme_lab = (const int*)d_in[3];    // [A]
    float*       out         = (float*)d_out;          // [BT, P]

    unsigned short* Wf = (unsigned short*)d_ws;        // 256 KB, fully rewritten

    build_Wf<<<CDIM / 32, 256, 0, stream>>>(alloW, phone_lab, phoneme_lab, Wf);
    allo_fused<<<BT / 32, 256, 0, stream>>>(hs, Wf, out);
}

// Round 6
// 100.126 us; speedup vs baseline: 1.0725x; 1.0004x over previous
//
#include <hip/hip_runtime.h>
#include <hip/hip_bf16.h>

// Problem constants (fixed by the reference):
//   B=16, T=1024 -> BT=16384 rows; C=512 phones; A=4096 arcs; P=256 phonemes.
#define BT   16384
#define CDIM 512
#define ADIM 4096
#define PDIM 256

typedef __attribute__((ext_vector_type(8))) short  short8;   // 8 x bf16 (4 VGPRs)
typedef __attribute__((ext_vector_type(8))) unsigned short ushort8;
typedef __attribute__((ext_vector_type(4))) float  f32x4;    // 4 x fp32 acc

// fp32 -> bf16 round-to-nearest-even (values are positive finite)
__device__ __forceinline__ unsigned short bf16_rne(float f) {
    unsigned int u = __float_as_uint(f);
    u += 0x7FFFu + ((u >> 16) & 1u);
    return (unsigned short)(u >> 16);
}

// ---------------------------------------------------------------------------
// Kernel 1: W build. 16 blocks x 32 phones. Each block scans the 4096 arcs
// once (labels read 16x total), accumulates W[c][p] in LDS, then emits one
// full kb-slab of the bf16 B-fragment-major layout:
//   Wf[kb][n][kin], kb = c>>5, kin = c&31;  block bx owns kb = bx.
// ---------------------------------------------------------------------------
__global__ __launch_bounds__(256) void build_Wf(const float* __restrict__ alloW,
                                                const int* __restrict__ phone_lab,
                                                const int* __restrict__ phoneme_lab,
                                                unsigned short* __restrict__ Wf) {
    __shared__ float wrow[32 * PDIM];   // 32 KB: [phone-within-block][phoneme]
    const int bx = blockIdx.x;          // 0..15 == kb
    const int t  = threadIdx.x;

#pragma unroll
    for (int i = 0; i < 32; ++i) wrow[i * 256 + t] = 0.0f;
    __syncthreads();

#pragma unroll
    for (int i = 0; i < ADIM / 256; ++i) {
        int a = i * 256 + t;
        int c = phone_lab[a];
        if ((c >> 5) == bx)
            atomicAdd(&wrow[(c & 31) * 256 + phoneme_lab[a]], __expf(alloW[a]));
    }
    __syncthreads();

    // thread t emits phoneme n=t: Wf[bx][t][0..31] (64 B contiguous)
    ushort8 pk[4];
#pragma unroll
    for (int g = 0; g < 4; ++g) {
#pragma unroll
        for (int j = 0; j < 8; ++j)
            pk[g][j] = bf16_rne(wrow[(g * 8 + j) * 256 + t]);
    }
    unsigned short* dst = Wf + (size_t)bx * (PDIM * 32) + t * 32;
#pragma unroll
    for (int g = 0; g < 4; ++g)
        *(ushort8*)(dst + g * 8) = pk[g];
}

// ---------------------------------------------------------------------------
// Kernel 2: fused exp + GEMM + redistribute + log.
// Block: 512 thr (8 waves), tile 64 rows x 256 cols. Grid 256 (1 block/CU,
// 8 waves/CU). Halves B L2 traffic vs 32-row tiles (256 KB Wf read per
// block; 67 MB total), and wave pairs (w, w+4) read identical B fragments
// (L1 hits). One prologue/epilogue instance per CU instead of two.
//
// Wave w: rowhalf = w>>2 (rows rowhalf*32..+31), cg = w&3 (cols cg*64..+63);
// per wave 2 row-frags x 4 col-frags of 16x16, K-step 32 (16x16x32 bf16).
//
// Prologue: 8 thr/row, e=exp(x) (no max-subtract: |hs|<~5.5), bf16-pack to
// A-frag LDS layout Af[rblk][kb][cc][kin] (64 KB); row Z via 3-step shfl;
// 1/Z folded into the epilogue by linearity.
// ---------------------------------------------------------------------------
__global__ __launch_bounds__(512, 2) void allo_fused(const float* __restrict__ hs,
                                                     const unsigned short* __restrict__ Wf,
                                                     float* __restrict__ out) {
    __shared__ __align__(16) unsigned short Af[4 * 16 * 16 * 32];  // 64 KB
    __shared__ float invZ[64];
    __shared__ float psum[4][64];

    const int tid  = threadIdx.x;
    const int wave = tid >> 6;
    const int lane = tid & 63;
    const int row0 = blockIdx.x * 64;

    // ---- prologue: stage bf16 e-values, compute row sums ----
    {
        const int r    = tid >> 3;       // 0..63 (row within tile)
        const int ksl  = tid & 7;        // k-slice within each kb
        const int rblk = r >> 4;
        const int cc   = r & 15;
        const float* hsr = hs + (size_t)(row0 + r) * CDIM + ksl * 4;
        unsigned short* af = Af + rblk * 8192 + cc * 32 + ksl * 4;

        float s = 0.0f;
#pragma unroll
        for (int h = 0; h < 2; ++h) {    // two batches of 8 kb-slabs
            float4 v[8];
#pragma unroll
            for (int i = 0; i < 8; ++i)
                v[i] = *(const float4*)(hsr + (h * 8 + i) * 32);
#pragma unroll
            for (int i = 0; i < 8; ++i) {
                float e0 = __expf(v[i].x), e1 = __expf(v[i].y);
                float e2 = __expf(v[i].z), e3 = __expf(v[i].w);
                s += (e0 + e1) + (e2 + e3);
                ushort4 pk;
                pk.x = bf16_rne(e0); pk.y = bf16_rne(e1);
                pk.z = bf16_rne(e2); pk.w = bf16_rne(e3);
                *(ushort4*)(af + (h * 8 + i) * 512) = pk;
            }
        }
        s += __shfl_xor(s, 1);
        s += __shfl_xor(s, 2);
        s += __shfl_xor(s, 4);
        if (ksl == 0) invZ[r] = 1.0f / s;
    }
    __syncthreads();

    // ---- MFMA K-loop ----
    const int c        = lane & 15;
    const int q        = lane >> 4;
    const int rowhalf  = wave >> 2;      // 0/1: rows rowhalf*32..+31
    const int cg       = wave & 3;       // col-group cg*64..+63

    f32x4 acc[2][4];
#pragma unroll
    for (int rb = 0; rb < 2; ++rb)
#pragma unroll
        for (int cb = 0; cb < 4; ++cb)
            acc[rb][cb] = (f32x4){0.f, 0.f, 0.f, 0.f};

    const unsigned short* wb  = Wf + (size_t)(cg * 64 + c) * 32 + q * 8;
    const unsigned short* af0 = Af + (size_t)rowhalf * 16384 + c * 32 + q * 8;

#pragma unroll 4
    for (int kb = 0; kb < 16; ++kb) {
        short8 a0 = *(const short8*)(af0 + kb * 512);
        short8 a1 = *(const short8*)(af0 + 8192 + kb * 512);

        const unsigned short* wkb = wb + (size_t)kb * 8192;
        short8 b0 = *(const short8*)(wkb);
        short8 b1 = *(const short8*)(wkb + 512);
        short8 b2 = *(const short8*)(wkb + 1024);
        short8 b3 = *(const short8*)(wkb + 1536);

        acc[0][0] = __builtin_amdgcn_mfma_f32_16x16x32_bf16(a0, b0, acc[0][0], 0, 0, 0);
        acc[0][1] = __builtin_amdgcn_mfma_f32_16x16x32_bf16(a0, b1, acc[0][1], 0, 0, 0);
        acc[0][2] = __builtin_amdgcn_mfma_f32_16x16x32_bf16(a0, b2, acc[0][2], 0, 0, 0);
        acc[0][3] = __builtin_amdgcn_mfma_f32_16x16x32_bf16(a0, b3, acc[0][3], 0, 0, 0);
        acc[1][0] = __builtin_amdgcn_mfma_f32_16x16x32_bf16(a1, b0, acc[1][0], 0, 0, 0);
        acc[1][1] = __builtin_amdgcn_mfma_f32_16x16x32_bf16(a1, b1, acc[1][1], 0, 0, 0);
        acc[1][2] = __builtin_amdgcn_mfma_f32_16x16x32_bf16(a1, b2, acc[1][2], 0, 0, 0);
        acc[1][3] = __builtin_amdgcn_mfma_f32_16x16x32_bf16(a1, b3, acc[1][3], 0, 0, 0);
    }

    // ---- epilogue ----
    // C/D mapping (m89/m91): col = lane&15 (=c), row = q*4 + reg.
    float sv[2][4];
#pragma unroll
    for (int rb = 0; rb < 2; ++rb)
#pragma unroll
        for (int r = 0; r < 4; ++r) {
            float x = (acc[rb][0][r] + acc[rb][1][r]) + (acc[rb][2][r] + acc[rb][3][r]);
            x += __shfl_xor(x, 1);
            x += __shfl_xor(x, 2);
            x += __shfl_xor(x, 4);
            x += __shfl_xor(x, 8);
            sv[rb][r] = x;   // this wave's 64-col partial for its row
        }
    if (c == 0) {
#pragma unroll
        for (int rb = 0; rb < 2; ++rb)
#pragma unroll
            for (int r = 0; r < 4; ++r)
                psum[cg][rowhalf * 32 + rb * 16 + q * 4 + r] = sv[rb][r];
    }
    __syncthreads();

#pragma unroll
    for (int rb = 0; rb < 2; ++rb)
#pragma unroll
        for (int r = 0; r < 4; ++r) {
            const int rr = rowhalf * 32 + rb * 16 + q * 4 + r;
            const float iz = invZ[rr];
            const float S  = ((psum[0][rr] + psum[1][rr]) + (psum[2][rr] + psum[3][rr])) * iz;
            const float corr = (S - 1.0f) * (1.0f / (float)PDIM);
            float* orow = out + (size_t)(row0 + rr) * PDIM + cg * 64 + c;
#pragma unroll
            for (int cb = 0; cb < 4; ++cb)
                orow[cb * 16] = __logf(acc[rb][cb][r] * iz - corr);
        }
}

// ---------------------------------------------------------------------------
extern "C" void kernel_launch(void* const* d_in, const int* in_sizes, int n_in,
                              void* d_out, int out_size, void* d_ws, size_t ws_size,
                              hipStream_t stream) {
    const float* hs          = (const float*)d_in[0];  // [BT, C]
    const float* alloW       = (const float*)d_in[1];  // [A]
    const int*   phone_lab   = (const int*)d_in[2];    // [A]
    const int*   phoneme_lab = (const int*)d_in[3];    // [A]
    float*       out         = (float*)d_out;          // [BT, P]

    unsigned short* Wf = (unsigned short*)d_ws;        // 256 KB, fully rewritten

    build_Wf<<<CDIM / 32, 256, 0, stream>>>(alloW, phone_lab, phoneme_lab, Wf);
    allo_fused<<<BT / 64, 512, 0, stream>>>(hs, Wf, out);
}

// Round 7
// 99.701 us; speedup vs baseline: 1.0771x; 1.0043x over previous
//
#include <hip/hip_runtime.h>
#include <hip/hip_bf16.h>

// Problem constants (fixed by the reference):
//   B=16, T=1024 -> BT=16384 rows; C=512 phones; A=4096 arcs; P=256 phonemes.
#define BT   16384
#define CDIM 512
#define ADIM 4096
#define PDIM 256

typedef __attribute__((ext_vector_type(8))) short  short8;   // 8 x bf16 (4 VGPRs)
typedef __attribute__((ext_vector_type(8))) unsigned short ushort8;
typedef __attribute__((ext_vector_type(4))) float  f32x4;    // 4 x fp32 acc

// fp32 -> bf16 round-to-nearest-even (values are positive finite)
__device__ __forceinline__ unsigned short bf16_rne(float f) {
    unsigned int u = __float_as_uint(f);
    u += 0x7FFFu + ((u >> 16) & 1u);
    return (unsigned short)(u >> 16);
}

// ---------------------------------------------------------------------------
// Kernel 1: W build. 16 blocks x 32 phones. Each block scans the 4096 arcs
// once (labels read 16x total), accumulates W[c][p] in LDS, emits one full
// kb-slab of the bf16 B-fragment layout Wf[kb][n][kin] (kb=c>>5, kin=c&31),
// AND the per-phone row sums rowsumW[c] = sum_p W[c][p] (for the prologue-
// computed redistribution term — kills the GEMM kernel's epilogue reduce).
// ---------------------------------------------------------------------------
__global__ __launch_bounds__(256) void build_Wf(const float* __restrict__ alloW,
                                                const int* __restrict__ phone_lab,
                                                const int* __restrict__ phoneme_lab,
                                                unsigned short* __restrict__ Wf,
                                                float* __restrict__ rowsumW) {
    __shared__ float wrow[32 * PDIM];   // 32 KB: [phone-within-block][phoneme]
    const int bx = blockIdx.x;          // 0..15 == kb
    const int t  = threadIdx.x;

#pragma unroll
    for (int i = 0; i < 32; ++i) wrow[i * 256 + t] = 0.0f;
    __syncthreads();

#pragma unroll
    for (int i = 0; i < ADIM / 256; ++i) {
        int a = i * 256 + t;
        int c = phone_lab[a];
        if ((c >> 5) == bx)
            atomicAdd(&wrow[(c & 31) * 256 + phoneme_lab[a]], __expf(alloW[a]));
    }
    __syncthreads();

    // thread t emits phoneme n=t: Wf[bx][t][0..31] (64 B contiguous)
    ushort8 pk[4];
#pragma unroll
    for (int g = 0; g < 4; ++g) {
#pragma unroll
        for (int j = 0; j < 8; ++j)
            pk[g][j] = bf16_rne(wrow[(g * 8 + j) * 256 + t]);
    }
    unsigned short* dst = Wf + (size_t)bx * (PDIM * 32) + t * 32;
#pragma unroll
    for (int g = 0; g < 4; ++g)
        *(ushort8*)(dst + g * 8) = pk[g];

    // rowsumW: row i = t>>3 (0..31), lane j = t&7 sums 32 phonemes
    {
        const int i = t >> 3, j = t & 7;
        float s = 0.0f;
#pragma unroll
        for (int m = 0; m < 32; ++m) s += wrow[i * 256 + j * 32 + m];
        s += __shfl_xor(s, 1);
        s += __shfl_xor(s, 2);
        s += __shfl_xor(s, 4);
        if (j == 0) rowsumW[bx * 32 + i] = s;
    }
}

// ---------------------------------------------------------------------------
// Kernel 2: fused exp + GEMM + redistribute + log.
// Block: 256 thr (4 waves), tile 32 rows x 256 cols. Grid 512 (2 blocks/CU).
//
// Prologue: 8 thr/row; batched float4 hs loads, e=exp(x) (no max-subtract:
// |hs|<~5.5), bf16-pack into A-frag LDS Af[rb][kb][cc][kin]. Row reductions
// computed HERE for both Z = sum_c e and S_u = sum_c e*rowsumW[c] (identity:
// sum_p (eW)[r,p] = sum_c e[r,c]*rowsumW[c]) -> invZ[r], corr[r] ready
// before the K-loop. 1/Z folded into the epilogue by linearity.
//
// K-loop: A from LDS (ds_read_b128), B from global Wf (frag-major, L2-hot),
// 8 MFMA 16x16x32 per wave per kb, compiler-scheduled (manual pipelining
// measured neutral in r5).
//
// Epilogue: pure per-lane out = log(u*invZ - corr) — no cross-wave reduce,
// no second barrier; waves retire independently.
// ---------------------------------------------------------------------------
__global__ __launch_bounds__(256, 2) void allo_fused(const float* __restrict__ hs,
                                                     const unsigned short* __restrict__ Wf,
                                                     const float* __restrict__ rowsumW,
                                                     float* __restrict__ out) {
    __shared__ __align__(16) unsigned short Af[2 * 16 * 16 * 32];  // 32 KB
    __shared__ float invZ[32];
    __shared__ float corrS[32];

    const int tid  = threadIdx.x;
    const int wave = tid >> 6;
    const int lane = tid & 63;
    const int row0 = blockIdx.x * 32;

    // ---- prologue ----
    {
        const int r   = tid >> 3;        // 0..31 (row within tile)
        const int ksl = tid & 7;         // k-slice within each kb
        const int rb  = r >> 4;
        const int cc  = r & 15;
        const float* hsr = hs + (size_t)(row0 + r) * CDIM + ksl * 4;
        const float* rsw = rowsumW + ksl * 4;
        unsigned short* af = Af + rb * 8192 + cc * 32 + ksl * 4;

        float s = 0.0f, sw = 0.0f;
#pragma unroll
        for (int h = 0; h < 2; ++h) {    // two batches of 8 kb-slabs
            float4 v[8], w[8];
#pragma unroll
            for (int i = 0; i < 8; ++i) {
                v[i] = *(const float4*)(hsr + (h * 8 + i) * 32);
                w[i] = *(const float4*)(rsw + (h * 8 + i) * 32);
            }
#pragma unroll
            for (int i = 0; i < 8; ++i) {
                float e0 = __expf(v[i].x), e1 = __expf(v[i].y);
                float e2 = __expf(v[i].z), e3 = __expf(v[i].w);
                s += (e0 + e1) + (e2 + e3);
                sw = fmaf(e0, w[i].x, sw); sw = fmaf(e1, w[i].y, sw);
                sw = fmaf(e2, w[i].z, sw); sw = fmaf(e3, w[i].w, sw);
                ushort4 pk;
                pk.x = bf16_rne(e0); pk.y = bf16_rne(e1);
                pk.z = bf16_rne(e2); pk.w = bf16_rne(e3);
                *(ushort4*)(af + (h * 8 + i) * 512) = pk;
            }
        }
        s  += __shfl_xor(s, 1);  sw += __shfl_xor(sw, 1);
        s  += __shfl_xor(s, 2);  sw += __shfl_xor(sw, 2);
        s  += __shfl_xor(s, 4);  sw += __shfl_xor(sw, 4);
        if (ksl == 0) {
            const float iz = 1.0f / s;
            invZ[r]  = iz;
            corrS[r] = (sw * iz - 1.0f) * (1.0f / (float)PDIM);
        }
    }
    __syncthreads();

    // ---- MFMA K-loop ----
    const int c = lane & 15;
    const int q = lane >> 4;

    f32x4 acc[2][4];
#pragma unroll
    for (int rb = 0; rb < 2; ++rb)
#pragma unroll
        for (int cb = 0; cb < 4; ++cb)
            acc[rb][cb] = (f32x4){0.f, 0.f, 0.f, 0.f};

    const unsigned short* wb  = Wf + (size_t)(wave * 64 + c) * 32 + q * 8;
    const unsigned short* af0 = Af + c * 32 + q * 8;

#pragma unroll 4
    for (int kb = 0; kb < 16; ++kb) {
        short8 a0 = *(const short8*)(af0 + kb * 512);
        short8 a1 = *(const short8*)(af0 + 8192 + kb * 512);

        const unsigned short* wkb = wb + (size_t)kb * 8192;
        short8 b0 = *(const short8*)(wkb);
        short8 b1 = *(const short8*)(wkb + 512);
        short8 b2 = *(const short8*)(wkb + 1024);
        short8 b3 = *(const short8*)(wkb + 1536);

        acc[0][0] = __builtin_amdgcn_mfma_f32_16x16x32_bf16(a0, b0, acc[0][0], 0, 0, 0);
        acc[0][1] = __builtin_amdgcn_mfma_f32_16x16x32_bf16(a0, b1, acc[0][1], 0, 0, 0);
        acc[0][2] = __builtin_amdgcn_mfma_f32_16x16x32_bf16(a0, b2, acc[0][2], 0, 0, 0);
        acc[0][3] = __builtin_amdgcn_mfma_f32_16x16x32_bf16(a0, b3, acc[0][3], 0, 0, 0);
        acc[1][0] = __builtin_amdgcn_mfma_f32_16x16x32_bf16(a1, b0, acc[1][0], 0, 0, 0);
        acc[1][1] = __builtin_amdgcn_mfma_f32_16x16x32_bf16(a1, b1, acc[1][1], 0, 0, 0);
        acc[1][2] = __builtin_amdgcn_mfma_f32_16x16x32_bf16(a1, b2, acc[1][2], 0, 0, 0);
        acc[1][3] = __builtin_amdgcn_mfma_f32_16x16x32_bf16(a1, b3, acc[1][3], 0, 0, 0);
    }

    // ---- epilogue: per-lane only ----
    // C/D mapping (m89/m91): col = lane&15 (=c), row = q*4 + reg.
#pragma unroll
    for (int rb = 0; rb < 2; ++rb)
#pragma unroll
        for (int r = 0; r < 4; ++r) {
            const int rr = rb * 16 + q * 4 + r;
            const float iz = invZ[rr];
            const float co = corrS[rr];
            float* orow = out + (size_t)(row0 + rr) * PDIM + wave * 64 + c;
#pragma unroll
            for (int cb = 0; cb < 4; ++cb)
                orow[cb * 16] = __logf(acc[rb][cb][r] * iz - co);
        }
}

// ---------------------------------------------------------------------------
extern "C" void kernel_launch(void* const* d_in, const int* in_sizes, int n_in,
                              void* d_out, int out_size, void* d_ws, size_t ws_size,
                              hipStream_t stream) {
    const float* hs          = (const float*)d_in[0];  // [BT, C]
    const float* alloW       = (const float*)d_in[1];  // [A]
    const int*   phone_lab   = (const int*)d_in[2];    // [A]
    const int*   phoneme_lab = (const int*)d_in[3];    // [A]
    float*       out         = (float*)d_out;          // [BT, P]

    // ws: Wf 256 KB at 0, rowsumW 2 KB after
    unsigned short* Wf      = (unsigned short*)d_ws;
    float*          rowsumW = (float*)((char*)d_ws + (256 << 10));

    build_Wf<<<CDIM / 32, 256, 0, stream>>>(alloW, phone_lab, phoneme_lab, Wf, rowsumW);
    allo_fused<<<BT / 32, 256, 0, stream>>>(hs, Wf, rowsumW, out);
}